// Round 9
// baseline (437.321 us; speedup 1.0000x reference)
//
#include <hip/hip_runtime.h>

#define NB 512   // batch
#define NS 512   // seq
#define NT 128   // tags

// Raw workgroup barrier WITHOUT the vmcnt(0) drain __syncthreads() forces:
// only LDS visibility (lgkmcnt) is required step-to-step; global ws stores
// and emission prefetches stream freely across barriers.
#define LDS_BARRIER()                                            \
    do {                                                         \
        asm volatile("s_waitcnt lgkmcnt(0)" ::: "memory");       \
        __builtin_amdgcn_s_barrier();                            \
        __builtin_amdgcn_sched_barrier(0);                       \
    } while (0)

// DPP quad-perm butterfly max over the 4 lanes of an aligned quad.
// quad_perm [1,0,3,2] = 0xB1 (xor 1), [2,3,0,1] = 0x4E (xor 2).
__device__ __forceinline__ float quad_max_dpp(float m) {
    float t1 = __int_as_float(__builtin_amdgcn_update_dpp(
        0, __float_as_int(m), 0xB1, 0xF, 0xF, true));
    m = fmaxf(m, t1);
    float t2 = __int_as_float(__builtin_amdgcn_update_dpp(
        0, __float_as_int(m), 0x4E, 0xF, 0xF, true));
    m = fmaxf(m, t2);
    return m;
}

// Max over 32 candidates: 8 float4 score groups + 32 register trans values.
// All indices compile-time (VGPR-resident); balanced tree for ILP.
__device__ __forceinline__ float max32(const float4* S, const float* tc) {
    float g[8];
    #pragma unroll
    for (int q = 0; q < 8; ++q) {
        g[q] = fmaxf(fmaxf(S[q].x + tc[4*q+0], S[q].y + tc[4*q+1]),
                     fmaxf(S[q].z + tc[4*q+2], S[q].w + tc[4*q+3]));
    }
    float m01 = fmaxf(g[0], g[1]), m23 = fmaxf(g[2], g[3]);
    float m45 = fmaxf(g[4], g[5]), m67 = fmaxf(g[6], g[7]);
    return fmaxf(fmaxf(m01, m23), fmaxf(m45, m67));
}

// ---------------------------------------------------------------------------
// FAST kernel: value-only forward DP, 2 tags/thread (G=2) + ballot backtrace.
//
// LDS-pipe analysis (R7/R8 evidence): wall tracks ds_read/shfl instruction
// count, not VALU. 256 threads, thread (j=tid>>2, h=tid&3) owns tags
// {j, j+64}, candidates i in [h*32,h*32+32): each 8x ds_read_b128 feeds TWO
// tags -> LDS wave-insts per CU-step halve vs R6 (128 -> 64). Combine across
// the 4 h-lanes stays pure quad-DPP (zero LDS-pipe ops). Max is associative
// -> partition bitwise exact.
// Scores double-buffered in LDS, padded quarters (stride 36 dwords):
//   broadcast ds_read_b128 addresses hit disjoint bank sets.
// Stores PRE-EMISSION max rows ws[b][t][j]; ws[b][0][j] = start_t[j]
//   (score_t = ws[t] + emis[t], bitwise identical to forward).
// Backtrace (verified round 6): M at step t is ws[t][tag] (one shfl);
//   first i with v_i == M via __ballot+ctz = exact jnp.argmax semantics.
// ---------------------------------------------------------------------------
__global__ __launch_bounds__(256, 1)
void crf_viterbi_fast(const float* __restrict__ emis,     // [B,S,T]
                      const float* __restrict__ start_t,  // [T]
                      const float* __restrict__ end_t,    // [T]
                      const float* __restrict__ trans,    // [T,T]
                      float* __restrict__ out_paths,      // [B,S] as float
                      float* __restrict__ out_score,      // [B]   as float
                      float* __restrict__ ws)             // [B,S,T] m-rows
{
    __shared__ __align__(16) float scp[2][144];   // quarters at dwords 0,36,72,108
    __shared__ float Tlds[NT * 129];              // trans, row stride 129 (backtrace)
    __shared__ float finv[NT];
    __shared__ unsigned char pathb[NS];

    const int b   = blockIdx.x;
    const int tid = threadIdx.x;
    const int j   = tid >> 2;    // tag pair owner: tags j (0..63) and j+64
    const int h   = tid & 3;     // candidate quarter: i in [h*32, h*32+32)

    // Stage transitions into padded LDS (used only by backtrace).
    for (int idx = tid; idx < NT * NT; idx += 256) {
        Tlds[(idx >> 7) * 129 + (idx & 127)] = trans[idx];
    }

    // This thread's transition columns: tcA[k]=trans[h*32+k][j],
    // tcB[k]=trans[h*32+k][j+64].
    float tcA[32], tcB[32];
    #pragma unroll
    for (int k = 0; k < 32; ++k) {
        tcA[k] = trans[(h * 32 + k) * NT + j];
        tcB[k] = trans[(h * 32 + k) * NT + j + 64];
    }

    const float* eb   = emis + (size_t)b * NS * NT;
    float*       wrow = ws   + (size_t)b * NS * NT;

    // Padded LDS slot for tag i: (i>>5)*36 + (i&31).
    const int jq0 = (j >> 5) * 36 + (j & 31);     // tag j (quarters 0,1)
    const int jq1 = ((j + 64) >> 5) * 36 + (j & 31);  // tag j+64 (quarters 2,3)

    // t = 0: score0 = start + e0; ws row 0 holds start (pre-emission part).
    float nsA, nsB;
    {
        float stA = start_t[j], stB = start_t[j + 64];
        nsA = stA + eb[j];
        nsB = stB + eb[j + 64];
        if (h == 0) {
            scp[0][jq0] = nsA;  scp[0][jq1] = nsB;
            wrow[j] = stA;      wrow[j + 64] = stB;
        }
    }
    LDS_BARRIER();

    float e0 = eb[NT + j];          // emissions for t=1, prefetched
    float e1 = eb[NT + j + 64];
    const float* ep = eb + 2 * NT;  // prefetch base (row t+1 = 2)
    float* wp = wrow + NT;          // ws row t = 1

    int cur = 0;
    for (int t = 1; t < NS; ++t) {
        float e0c = e0, e1c = e1;
        if (t < NS - 1) {           // uniform branch; pointer-increment addr
            e0 = ep[j];
            e1 = ep[j + 64];
            ep += NT;
        }

        const float4* s4 = (const float4*)&scp[cur][h * 36];
        float4 S[8];
        #pragma unroll
        for (int q = 0; q < 8; ++q) S[q] = s4[q];   // 8 broadcast b128 reads

        // Two tags from the same 32 scores (the G=2 reuse).
        float mA = max32(S, tcA);
        float mB = max32(S, tcB);

        // Combine the 4 h-lanes (one aligned quad): pure VALU, no LDS pipe.
        mA = quad_max_dpp(mA);
        mB = quad_max_dpp(mB);

        nsA = mA + e0c;             // emission added AFTER max (ref order)
        nsB = mB + e1c;
        if (h == 0) {
            scp[cur ^ 1][jq0] = nsA;   // 16 lanes/wave, consecutive dwords
            scp[cur ^ 1][jq1] = nsB;
            wp[j]      = mA;           // PRE-emission max rows
            wp[j + 64] = mB;
        }
        wp += NT;
        LDS_BARRIER();                 // LDS-only barrier (no vmcnt drain)
        cur ^= 1;
    }

    // Final scores for backtrace seed.
    if (h == 0) {
        finv[j]      = nsA + end_t[j];
        finv[j + 64] = nsB + end_t[j + 64];
    }
    __syncthreads();    // full drain once: ws stores must be visible below

    // ---- backtrace: wave 0 only (verified round 6) ----
    if (tid < 64) {
        const int l = tid;

        // Seed: first-max over final scores (exact jnp.argmax semantics).
        float f0 = finv[l], f1 = finv[l + 64];
        float mv = fmaxf(f0, f1);
        mv = fmaxf(mv, __shfl_xor(mv, 1));
        mv = fmaxf(mv, __shfl_xor(mv, 2));
        mv = fmaxf(mv, __shfl_xor(mv, 4));
        mv = fmaxf(mv, __shfl_xor(mv, 8));
        mv = fmaxf(mv, __shfl_xor(mv, 16));
        mv = fmaxf(mv, __shfl_xor(mv, 32));
        unsigned long long b0 = __ballot(f0 == mv);
        unsigned long long b1 = __ballot(f1 == mv);
        int tag = b0 ? (int)__builtin_ctzll(b0) : 64 + (int)__builtin_ctzll(b1);
        if (l == 0) {
            out_score[b] = mv;
            pathb[NS - 1] = (unsigned char)tag;
        }

        // wM = raw m-row t (M source); a = score row t-1 = m-row + e-row.
        float wM0 = wrow[(size_t)(NS - 1) * NT + l];
        float wM1 = wrow[(size_t)(NS - 1) * NT + l + 64];
        float cw0 = wrow[(size_t)(NS - 2) * NT + l];
        float cw1 = wrow[(size_t)(NS - 2) * NT + l + 64];
        float a0  = cw0 + eb[(size_t)(NS - 2) * NT + l];
        float a1  = cw1 + eb[(size_t)(NS - 2) * NT + l + 64];

        for (int t = NS - 1; t >= 1; --t) {
            // Prefetch rows t-2 (clamped; dead at t=1).
            const int tp = (t >= 2) ? t - 2 : 0;
            float pw0 = wrow[(size_t)tp * NT + l];
            float pw1 = wrow[(size_t)tp * NT + l + 64];
            float pe0 = eb[(size_t)tp * NT + l];
            float pe1 = eb[(size_t)tp * NT + l + 64];

            // Max value for step t: M = m(t, tag) -- no reduction needed.
            float wsel = (tag >= 64) ? wM1 : wM0;   // tag is wave-uniform
            float M = __shfl(wsel, tag & 63);

            float v0 = a0 + Tlds[l * 129 + tag];          // 2-way bank alias: free
            float v1 = a1 + Tlds[(l + 64) * 129 + tag];
            unsigned long long c0 = __ballot(v0 == M);
            unsigned long long c1 = __ballot(v1 == M);
            tag = c0 ? (int)__builtin_ctzll(c0) : 64 + (int)__builtin_ctzll(c1);
            if (l == 0) pathb[t - 1] = (unsigned char)tag;

            // Roll: M source for step t-1 is m-row t-1 (= cw); candidates t-2.
            wM0 = cw0; wM1 = cw1;
            a0 = pw0 + pe0; a1 = pw1 + pe1;
            cw0 = pw0; cw1 = pw1;
        }
    }
    __syncthreads();

    // Coalesced path write: first 128 threads write t = tid, tid+128, ...
    if (tid < NT) {
        float* op = out_paths + (size_t)b * NS;
        #pragma unroll
        for (int k = 0; k < NS / NT; ++k) {
            op[k * NT + tid] = (float)pathb[k * NT + tid];
        }
    }
}

// ---------------------------------------------------------------------------
// FALLBACK (round-4 kernel, verified): used only if ws_size < 128 MiB.
// ---------------------------------------------------------------------------
__global__ __launch_bounds__(512, 1)
void crf_viterbi_fb(const float* __restrict__ emis,
                    const float* __restrict__ start_t,
                    const float* __restrict__ end_t,
                    const float* __restrict__ trans,
                    float* __restrict__ out_paths,
                    float* __restrict__ out_score)
{
    __shared__ __align__(16) float scp[2][144];
    __shared__ unsigned int histw[NS / 4][NT];
    __shared__ unsigned char pathb[NS];

    const int b   = blockIdx.x;
    const int tid = threadIdx.x;
    const int j   = tid >> 2;
    const int h   = tid & 3;

    float tc[32];
    #pragma unroll
    for (int k = 0; k < 32; ++k) tc[k] = trans[(h * 32 + k) * NT + j];

    const float* eb = emis + (size_t)b * NS * NT;
    const int jq = (j >> 5) * 36 + (j & 31);

    float ns = start_t[j] + eb[j];
    if (h == 0) scp[0][jq] = ns;
    __syncthreads();

    float e_next = eb[NT + j];
    unsigned int packed = 0;
    int cur = 0;
    for (int t = 1; t < NS; ++t) {
        float e_cur = e_next;
        int tn = (t + 1 < NS) ? (t + 1) : (NS - 1);
        e_next = eb[(size_t)tn * NT + j];

        const float4* s4 = (const float4*)&scp[cur][h * 36];
        float m0 = -INFINITY, m1 = -INFINITY;
        int x0 = 0, x1 = 0;
        #pragma unroll
        for (int q = 0; q < 4; ++q) {
            float4 A  = s4[q];
            float4 Bv = s4[4 + q];
            float v;
            v = A.x  + tc[4*q+0];     if (v > m0) { m0 = v; x0 = 4*q+0; }
            v = A.y  + tc[4*q+1];     if (v > m0) { m0 = v; x0 = 4*q+1; }
            v = A.z  + tc[4*q+2];     if (v > m0) { m0 = v; x0 = 4*q+2; }
            v = A.w  + tc[4*q+3];     if (v > m0) { m0 = v; x0 = 4*q+3; }
            v = Bv.x + tc[16+4*q+0];  if (v > m1) { m1 = v; x1 = 4*q+0; }
            v = Bv.y + tc[16+4*q+1];  if (v > m1) { m1 = v; x1 = 4*q+1; }
            v = Bv.z + tc[16+4*q+2];  if (v > m1) { m1 = v; x1 = 4*q+2; }
            v = Bv.w + tc[16+4*q+3];  if (v > m1) { m1 = v; x1 = 4*q+3; }
        }
        if (m1 > m0) { m0 = m1; x0 = x1 + 16; }
        float m = m0;
        int   x = h * 32 + x0;

        float mo = __shfl_xor(m, 1);
        int   xo = __shfl_xor(x, 1);
        float mlo = (h & 1) ? mo : m;  int xlo = (h & 1) ? xo : x;
        float mhi = (h & 1) ? m : mo;  int xhi = (h & 1) ? x : xo;
        if (mhi > mlo) { m = mhi; x = xhi; } else { m = mlo; x = xlo; }
        mo = __shfl_xor(m, 2);
        xo = __shfl_xor(x, 2);
        mlo = (h & 2) ? mo : m;  xlo = (h & 2) ? xo : x;
        mhi = (h & 2) ? m : mo;  xhi = (h & 2) ? x : xo;
        if (mhi > mlo) { m = mhi; x = xhi; } else { m = mlo; x = xlo; }

        ns = m + e_cur;
        packed |= (unsigned int)x << (8 * ((t - 1) & 3));
        if (h == 0) {
            if ((((t - 1) & 3) == 3) || (t == NS - 1))
                histw[(t - 1) >> 2][j] = packed;
            scp[cur ^ 1][jq] = ns;
        }
        if (((t - 1) & 3) == 3) packed = 0;
        __syncthreads();
        cur ^= 1;
    }

    float fin = ns + end_t[j];
    if (h == 0) scp[0][jq] = fin;
    __syncthreads();

    if (tid == 0) {
        float bm = scp[0][0]; int bi = 0;
        for (int i = 1; i < NT; ++i) {
            float v = scp[0][(i >> 5) * 36 + (i & 31)];
            if (v > bm) { bm = v; bi = i; }
        }
        out_score[b] = bm;
        int tag = bi;
        pathb[NS - 1] = (unsigned char)tag;
        for (int t = NS - 1; t >= 1; --t) {
            int idx = t - 1;
            unsigned int w = histw[idx >> 2][tag];
            tag = (int)((w >> (8 * (idx & 3))) & 0xFFu);
            pathb[t - 1] = (unsigned char)tag;
        }
    }
    __syncthreads();

    if (tid < NT) {
        float* op = out_paths + (size_t)b * NS;
        #pragma unroll
        for (int k = 0; k < NS / NT; ++k) {
            op[k * NT + tid] = (float)pathb[k * NT + tid];
        }
    }
}

extern "C" void kernel_launch(void* const* d_in, const int* in_sizes, int n_in,
                              void* d_out, int out_size, void* d_ws, size_t ws_size,
                              hipStream_t stream) {
    const float* emis    = (const float*)d_in[0];
    // d_in[1] = mask: all ones, ignored (seq_ends = S-1 everywhere)
    const float* start_t = (const float*)d_in[2];
    const float* end_t   = (const float*)d_in[3];
    const float* trans   = (const float*)d_in[4];

    float* paths = (float*)d_out;                       // [B,S] as float
    float* score = (float*)d_out + (size_t)NB * NS;     // [B]   as float

    const size_t need = (size_t)NB * NS * NT * sizeof(float);   // 128 MiB
    if (ws_size >= need) {
        crf_viterbi_fast<<<NB, 256, 0, stream>>>(emis, start_t, end_t, trans,
                                                 paths, score, (float*)d_ws);
    } else {
        crf_viterbi_fb<<<NB, 512, 0, stream>>>(emis, start_t, end_t, trans,
                                               paths, score);
    }
}